// Round 8
// baseline (140.708 us; speedup 1.0000x reference)
//
#include <hip/hip_runtime.h>

// Problem constants (static per reference setup_inputs)
#define BB     16
#define HH     128
#define WW     8192
#define N_MAXC 128
#define W_OUTC 6271
#define SEP_CLASS 2.0f

// d_out layout (all float32): x_new [B*H*W_OUT] | xi_new [B*N_MAX*2] | xl_new [B*W_OUT]
#define X_ELEMS (BB * HH * W_OUTC)            // 12,843,008
#define XI_OFF  (X_ELEMS)
#define XL_OFF  (X_ELEMS + BB * N_MAXC * 2)

#define TCOLS 512
#define HROWS 16
#define NTILE 13                              // ceil(6271/512)
#define WS_INTS (BB * 2 * N_MAXC)             // sn+en per batch = 4096 ints (16KB)

typedef float vf4u __attribute__((ext_vector_type(4), aligned(4)));  // 4B-aligned ok
typedef int   vi4  __attribute__((ext_vector_type(4)));

// Reference map_col (verified rounds 2-7): >=0 src | -1 sep | -2 zero.
__device__ __forceinline__ int map_col_lds(int t, int Nb,
                                           const int* s_s0, const int* s_e0,
                                           const int* s_sn, const int* s_en) {
    int lo = 0, hi = Nb;
    while (lo < hi) { int mid = (lo + hi) >> 1; if (s_en[mid] <= t) lo = mid + 1; else hi = mid; }
    const int i  = lo;
    const int ic = (i < N_MAXC - 1) ? i : (N_MAXC - 1);
    if (i < Nb) {
        int sn = s_sn[ic], en = s_en[ic];
        if (t >= sn && en > sn && s_e0[ic] > s_s0[ic]) {
            int src = s_s0[ic] + (t - sn);
            return src < 0 ? 0 : (src > WW - 1 ? WW - 1 : src);
        }
    }
    if (i >= 1) {
        int ep = s_en[i - 1];
        if (t == ep && (i - 1) < (Nb - 1) && ep < WW) return -1;
    }
    return -2;
}

// ---------------- kernel 1: scan -> ws (sn,en) + xi_new ----------------
__global__ __launch_bounds__(128) void tb_scan(const int* __restrict__ xi,
                                               const int* __restrict__ Nv,
                                               float* __restrict__ out,
                                               int* __restrict__ ws) {
    __shared__ int s_scan[N_MAXC];
    const int b   = blockIdx.x;
    const int tid = threadIdx.x;
    const int Nb  = Nv[b];
    int2 se = ((const int2*)xi)[b * N_MAXC + tid];
    int w = se.y - se.x; if (w < 0) w = 0;
    const int wv = (tid < Nb) ? w : 0;
    s_scan[tid] = wv;
    __syncthreads();
    #pragma unroll
    for (int off = 1; off < N_MAXC; off <<= 1) {
        int v = (tid >= off) ? s_scan[tid - off] : 0;
        __syncthreads();
        s_scan[tid] += v;
        __syncthreads();
    }
    const int c  = s_scan[tid];
    const int sn = c - wv + tid;
    const int en = c + tid;
    ws[b * 2 * N_MAXC + tid]          = sn;
    ws[b * 2 * N_MAXC + N_MAXC + tid] = en;
    const bool valid = tid < Nb;
    out[XI_OFF + (b * N_MAXC + tid) * 2 + 0] = valid ? (float)sn : 0.0f;
    out[XI_OFF + (b * N_MAXC + tid) * 2 + 1] = valid ? (float)en : 0.0f;
}

// ---------------- kernel 2: bulk gather (+ xl_new on y==0) ----------------
__global__ __launch_bounds__(256) void tb_gather(const float* __restrict__ x,
                                                 const int* __restrict__ xi,
                                                 const int* __restrict__ Nv,
                                                 const int* __restrict__ xl,
                                                 const float* __restrict__ sep_param,
                                                 const int* __restrict__ ws,
                                                 float* __restrict__ out) {
    __shared__ int s_sn[N_MAXC], s_en[N_MAXC], s_s0[N_MAXC], s_e0[N_MAXC];
    const int t0  = blockIdx.x * TCOLS;
    const int h0  = blockIdx.y * HROWS;
    const int b   = blockIdx.z;
    const int tid = threadIdx.x;
    const int Nb  = Nv[b];

    if (tid < N_MAXC) {
        s_sn[tid] = ws[b * 2 * N_MAXC + tid];
        s_en[tid] = ws[b * 2 * N_MAXC + N_MAXC + tid];
        int2 se = ((const int2*)xi)[b * N_MAXC + tid];
        s_s0[tid] = se.x; s_e0[tid] = se.y;
    }
    __syncthreads();

    const float sep = sep_param[0];
    const float* xb = x   + ((size_t)b << 20);              // b*128*8192
    float*       ob = out + (size_t)b * (HH * (size_t)W_OUTC);

    // xl_new (208 blocks only)
    if (blockIdx.y == 0) {
        #pragma unroll
        for (int q = 0; q < 2; ++q) {
            const int t = t0 + tid + q * 256;
            if (t < W_OUTC) {
                const int m = map_col_lds(t, Nb, s_s0, s_e0, s_sn, s_en);
                float v = (m >= 0) ? (float)xl[b * WW + m] : ((m == -1) ? SEP_CLASS : 0.0f);
                out[XL_OFF + b * W_OUTC + t] = v;
            }
        }
    }

    const int c  = tid & 127;          // chunk: cols tA..tA+3
    const int rb = tid >> 7;           // row parity
    const int tA = t0 + 4 * c;

    // one binary search on tA; whole-chunk-in-one-chirp fast path
    int lo = 0, hi = Nb;
    while (lo < hi) { int mid = (lo + hi) >> 1; if (s_en[mid] <= tA) lo = mid + 1; else hi = mid; }
    const int i = lo;
    bool fast = false; int src = 0;
    if (tA + 3 < W_OUTC && i < Nb) {
        const int sn = s_sn[i], en = s_en[i];
        if (tA >= sn && tA + 3 < en && s_e0[i] > s_s0[i]) {   // 4 cols share i, all in-chirp
            fast = true;
            src  = s_s0[i] + (tA - sn);                        // in [0, 8176): no clamp needed
        }
    }

    if (fast) {
        #pragma unroll
        for (int rr = 0; rr < HROWS / 2; ++rr) {
            const int h = h0 + rb + rr * 2;
            const vf4u v = *(const vf4u*)(xb + ((size_t)h << 13) + src);
            *(vf4u*)(ob + (size_t)h * W_OUTC + tA) = v;
        }
    } else {
        int m[4];
        #pragma unroll
        for (int kk = 0; kk < 4; ++kk) {
            const int t = tA + kk;
            m[kk] = (t < W_OUTC) ? map_col_lds(t, Nb, s_s0, s_e0, s_sn, s_en) : -3;  // -3 = skip
        }
        #pragma unroll
        for (int rr = 0; rr < HROWS / 2; ++rr) {
            const int h = h0 + rb + rr * 2;
            const float* xr   = xb + ((size_t)h << 13);
            float*       orow = ob + (size_t)h * W_OUTC;
            #pragma unroll
            for (int kk = 0; kk < 4; ++kk) {
                const int mm = m[kk];
                if (mm != -3) {
                    orow[tA + kk] = (mm >= 0) ? xr[mm] : ((mm == -1) ? sep : 0.0f);
                }
            }
        }
    }
}

// ---------------- fallback (no ws): round-7 fused kernel (verified) ----------------
__global__ __launch_bounds__(256, 4) void tb_fused(const float* __restrict__ x,
                                                   const int* __restrict__ xi,
                                                   const int* __restrict__ Nv,
                                                   const int* __restrict__ xl,
                                                   const float* __restrict__ sep_param,
                                                   float* __restrict__ out) {
    __shared__ int s_s0[N_MAXC], s_e0[N_MAXC], s_scan[N_MAXC], s_sn[N_MAXC], s_en[N_MAXC];
    __shared__ __align__(16) int s_map[TCOLS];
    const int t0  = blockIdx.x * TCOLS;
    const int h0  = blockIdx.y * HROWS;
    const int b   = blockIdx.z;
    const int tid = threadIdx.x;
    const int Nb  = Nv[b];
    int wv = 0;
    if (tid < N_MAXC) {
        int2 se = ((const int2*)xi)[b * N_MAXC + tid];
        s_s0[tid] = se.x; s_e0[tid] = se.y;
        int w = se.y - se.x; if (w < 0) w = 0;
        wv = (tid < Nb) ? w : 0;
        s_scan[tid] = wv;
    }
    __syncthreads();
    #pragma unroll
    for (int off = 1; off < N_MAXC; off <<= 1) {
        int v = 0;
        if (tid < N_MAXC && tid >= off) v = s_scan[tid - off];
        __syncthreads();
        if (tid < N_MAXC) s_scan[tid] += v;
        __syncthreads();
    }
    if (tid < N_MAXC) {
        int c = s_scan[tid];
        s_sn[tid] = c - wv + tid;
        s_en[tid] = c + tid;
    }
    __syncthreads();
    #pragma unroll
    for (int q = 0; q < 2; ++q) {
        const int j = tid + q * 256;
        const int t = t0 + j;
        s_map[j] = (t < W_OUTC) ? map_col_lds(t, Nb, s_s0, s_e0, s_sn, s_en) : -2;
    }
    if (blockIdx.y == 0 && blockIdx.x == 0 && tid < N_MAXC) {
        const bool valid = tid < Nb;
        out[XI_OFF + (b * N_MAXC + tid) * 2 + 0] = valid ? (float)s_sn[tid] : 0.0f;
        out[XI_OFF + (b * N_MAXC + tid) * 2 + 1] = valid ? (float)s_en[tid] : 0.0f;
    }
    __syncthreads();
    if (blockIdx.y == 0) {
        #pragma unroll
        for (int q = 0; q < 2; ++q) {
            const int j = tid + q * 256;
            const int t = t0 + j;
            if (t < W_OUTC) {
                const int m = s_map[j];
                float v = (m >= 0) ? (float)xl[b * WW + m] : ((m == -1) ? SEP_CLASS : 0.0f);
                out[XL_OFF + b * W_OUTC + t] = v;
            }
        }
    }
    const float sep = sep_param[0];
    const int   c   = tid & 127;
    const int   rb  = tid >> 7;
    const vi4   mv  = ((const vi4*)s_map)[c];
    const int   tA  = t0 + 4 * c;
    const float* xb = x   + ((size_t)b << 20);
    float*       ob = out + (size_t)b * (HH * W_OUTC);
    const unsigned a0 = (mv.x >= 0) ? (unsigned)mv.x : 0u;
    const unsigned a1 = (mv.y >= 0) ? (unsigned)mv.y : 0u;
    const unsigned a2 = (mv.z >= 0) ? (unsigned)mv.z : 0u;
    const unsigned a3 = (mv.w >= 0) ? (unsigned)mv.w : 0u;
    const float f0 = (mv.x == -1) ? sep : 0.0f;
    const float f1 = (mv.y == -1) ? sep : 0.0f;
    const float f2 = (mv.z == -1) ? sep : 0.0f;
    const float f3 = (mv.w == -1) ? sep : 0.0f;
    if (tA + 3 < W_OUTC) {
        #pragma unroll
        for (int rr = 0; rr < HROWS / 2; ++rr) {
            const int h = h0 + rb + rr * 2;
            const float* xr = xb + ((size_t)h << 13);
            float* orow = ob + (size_t)h * W_OUTC + tA;
            const float v0 = (mv.x >= 0) ? xr[a0] : f0;
            const float v1 = (mv.y >= 0) ? xr[a1] : f1;
            const float v2 = (mv.z >= 0) ? xr[a2] : f2;
            const float v3 = (mv.w >= 0) ? xr[a3] : f3;
            orow[0] = v0; orow[1] = v1; orow[2] = v2; orow[3] = v3;
        }
    } else if (tA < W_OUTC) {
        const int nrem = W_OUTC - tA;
        #pragma unroll
        for (int rr = 0; rr < HROWS / 2; ++rr) {
            const int h = h0 + rb + rr * 2;
            const float* xr = xb + ((size_t)h << 13);
            float* orow = ob + (size_t)h * W_OUTC + tA;
            if (nrem > 0) orow[0] = (mv.x >= 0) ? xr[a0] : f0;
            if (nrem > 1) orow[1] = (mv.y >= 0) ? xr[a1] : f1;
            if (nrem > 2) orow[2] = (mv.z >= 0) ? xr[a2] : f2;
        }
    }
}

extern "C" void kernel_launch(void* const* d_in, const int* in_sizes, int n_in,
                              void* d_out, int out_size, void* d_ws, size_t ws_size,
                              hipStream_t stream) {
    const float* x   = (const float*)d_in[0];
    const int*   xi  = (const int*)  d_in[1];
    const int*   Nv  = (const int*)  d_in[2];
    const int*   xl  = (const int*)  d_in[3];
    const float* sep = (const float*)d_in[4];
    float*       out = (float*)d_out;

    dim3 grid(NTILE, HH / HROWS, BB);         // 13 x 8 x 16 = 1664 blocks

    if (d_ws && ws_size >= WS_INTS * sizeof(int)) {
        int* ws = (int*)d_ws;
        tb_scan<<<dim3(BB), dim3(128), 0, stream>>>(xi, Nv, out, ws);
        tb_gather<<<grid, dim3(256), 0, stream>>>(x, xi, Nv, xl, sep, ws, out);
    } else {
        tb_fused<<<grid, dim3(256), 0, stream>>>(x, xi, Nv, xl, sep, out);
    }
}

// Round 9
// 126.387 us; speedup vs baseline: 1.1133x; 1.1133x over previous
//
#include <hip/hip_runtime.h>

// Problem constants (static per reference setup_inputs)
#define BB     16
#define HH     128
#define WW     8192
#define N_MAXC 128
#define W_OUTC 6271
#define SEP_CLASS 2.0f

// d_out layout (all float32): x_new [B*H*W_OUT] | xi_new [B*N_MAX*2] | xl_new [B*W_OUT]
#define X_ELEMS (BB * HH * W_OUTC)            // 12,843,008
#define XI_OFF  (X_ELEMS)
#define XL_OFF  (X_ELEMS + BB * N_MAXC * 2)

#define WS_INTS (BB * 2 * N_MAXC)             // sn+en per batch (16KB)

// tb_main roles
#define NCOPY 2048                            // 16 chirpgroups x 8 rowgroups x 16 b
#define NFILL 128                             // 8 rowgroups x 16 b
#define NAUX  208                             // 13 tiles x 16 b
#define NBLK  (NCOPY + NFILL + NAUX)

typedef float vf4u __attribute__((ext_vector_type(4), aligned(4)));

// Reference map_col (verified R2-R8): >=0 src | -1 sep | -2 zero.
__device__ __forceinline__ int map_col_lds(int t, int Nb,
                                           const int* s_s0, const int* s_e0,
                                           const int* s_sn, const int* s_en) {
    int lo = 0, hi = Nb;
    while (lo < hi) { int mid = (lo + hi) >> 1; if (s_en[mid] <= t) lo = mid + 1; else hi = mid; }
    const int i  = lo;
    const int ic = (i < N_MAXC - 1) ? i : (N_MAXC - 1);
    if (i < Nb) {
        int sn = s_sn[ic], en = s_en[ic];
        if (t >= sn && en > sn && s_e0[ic] > s_s0[ic]) {
            int src = s_s0[ic] + (t - sn);
            return src < 0 ? 0 : (src > WW - 1 ? WW - 1 : src);
        }
    }
    if (i >= 1) {
        int ep = s_en[i - 1];
        if (t == ep && (i - 1) < (Nb - 1) && ep < WW) return -1;
    }
    return -2;
}

// ---------------- kernel 1: scan -> ws (sn,en) + xi_new (verified R8) ----------------
__global__ __launch_bounds__(128) void tb_scan(const int* __restrict__ xi,
                                               const int* __restrict__ Nv,
                                               float* __restrict__ out,
                                               int* __restrict__ ws) {
    __shared__ int s_scan[N_MAXC];
    const int b   = blockIdx.x;
    const int tid = threadIdx.x;
    const int Nb  = Nv[b];
    int2 se = ((const int2*)xi)[b * N_MAXC + tid];
    int w = se.y - se.x; if (w < 0) w = 0;
    const int wv = (tid < Nb) ? w : 0;
    s_scan[tid] = wv;
    __syncthreads();
    #pragma unroll
    for (int off = 1; off < N_MAXC; off <<= 1) {
        int v = (tid >= off) ? s_scan[tid - off] : 0;
        __syncthreads();
        s_scan[tid] += v;
        __syncthreads();
    }
    const int c  = s_scan[tid];
    const int sn = c - wv + tid;
    const int en = c + tid;
    ws[b * 2 * N_MAXC + tid]          = sn;
    ws[b * 2 * N_MAXC + N_MAXC + tid] = en;
    const bool valid = tid < Nb;
    out[XI_OFF + (b * N_MAXC + tid) * 2 + 0] = valid ? (float)sn : 0.0f;
    out[XI_OFF + (b * N_MAXC + tid) * 2 + 1] = valid ? (float)en : 0.0f;
}

// ---------------- kernel 2: role-dispatched main ----------------
__global__ __launch_bounds__(256) void tb_main(const float* __restrict__ x,
                                               const int* __restrict__ xi,
                                               const int* __restrict__ Nv,
                                               const int* __restrict__ xl,
                                               const float* __restrict__ sep_param,
                                               const int* __restrict__ ws,
                                               float* __restrict__ out) {
    __shared__ int s_buf[512];                 // union across roles (2KB)
    const int bid = blockIdx.x;
    const int tid = threadIdx.x;

    if (bid < NCOPY) {
        // ======== copy role: 8 chirps x 16 rows, pure float4 chirp copy ========
        const int cg = bid >> 7;               // 0..15 chirp group
        const int rg = (bid >> 4) & 7;         // 0..7 row group
        const int b  = bid & 15;
        const int Nb = Nv[b];
        int* s_s0 = s_buf;      // [8]
        int* s_sn = s_buf + 8;  // [8]
        int* s_w  = s_buf + 16; // [8]
        int* s_sp = s_buf + 24; // [8] separator col (or -1)
        if (tid < 8) {
            const int i  = cg * 8 + tid;
            const int sn = ws[b * 2 * N_MAXC + i];
            const int en = ws[b * 2 * N_MAXC + N_MAXC + i];
            int2 se = ((const int2*)xi)[b * N_MAXC + i];
            int w = se.y - se.x; if (w < 0) w = 0;
            const bool valid = (i < Nb) && (w > 0);
            s_s0[tid] = valid ? se.x : 0;
            s_sn[tid] = valid ? sn   : 0;
            s_w[tid]  = valid ? w    : 0;
            s_sp[tid] = (i < Nb - 1 && en < WW) ? en : -1;
        }
        __syncthreads();

        const int h0 = rg * 16;
        const float sep = sep_param[0];
        const float* xb = x   + ((size_t)(b * HH + h0) << 13);
        float*       ob = out + (size_t)(b * HH + h0) * W_OUTC;

        // 1536 units (16 rows x 8 chirps x 12 chunks), 6 per thread, phase-batched
        unsigned ur[6], us[6], ud[6]; bool ua[6], uf[6]; unsigned uw[6], urem[6];
        #pragma unroll
        for (int p = 0; p < 6; ++p) {
            const unsigned unit = (unsigned)tid + (unsigned)p * 256u;
            const unsigned r = unit / 96u;           // row 0..15
            const unsigned q = unit - r * 96u;       // 0..95
            const unsigned j = q / 12u;              // chirp 0..7
            const unsigned k = q - j * 12u;          // chunk 0..11
            const unsigned w = (unsigned)s_w[j];
            ur[p] = r;
            us[p] = (unsigned)s_s0[j] + 4u * k;
            ud[p] = (unsigned)s_sn[j] + 4u * k;
            uw[p] = w;
            ua[p] = (4u * k < w);
            uf[p] = (4u * k + 4u <= w);
            urem[p] = w - 4u * k;                    // valid elems if partial
        }
        vf4u vv[6];
        #pragma unroll
        for (int p = 0; p < 6; ++p) {
            if (ua[p]) vv[p] = *(const vf4u*)(xb + ((size_t)ur[p] << 13) + us[p]);
        }
        #pragma unroll
        for (int p = 0; p < 6; ++p) {
            if (uf[p]) {
                *(vf4u*)(ob + (size_t)ur[p] * W_OUTC + ud[p]) = vv[p];
            } else if (ua[p]) {                       // ragged tail chunk (w%4)
                float* dd = ob + (size_t)ur[p] * W_OUTC + ud[p];
                if (urem[p] > 0) dd[0] = vv[p].x;
                if (urem[p] > 1) dd[1] = vv[p].y;
                if (urem[p] > 2) dd[2] = vv[p].z;
            }
        }
        // separators: 8 chirps x 16 rows = 128 predicated scalar stores
        if (tid < 128) {
            const int j = tid >> 4, r = tid & 15;
            const int pos = s_sp[j];
            if (pos >= 0) ob[(size_t)r * W_OUTC + pos] = sep;
        }
    } else if (bid < NCOPY + NFILL) {
        // ======== fill role: zero tail [en_{Nb-1}, W_OUT) for 16 rows ========
        const int fid = bid - NCOPY;
        const int rg  = fid >> 4;              // 0..7
        const int b   = fid & 15;
        const int Nb  = Nv[b];
        int zstart = (Nb > 0) ? ws[b * 2 * N_MAXC + N_MAXC + (Nb - 1)] : 0;
        if (zstart < 0) zstart = 0;
        float* ob = out + (size_t)(b * HH + rg * 16) * W_OUTC;
        for (int r = 0; r < 16; ++r) {
            float* orow = ob + (size_t)r * W_OUTC;
            for (int t = zstart + tid; t < W_OUTC; t += 256) orow[t] = 0.0f;
        }
    } else {
        // ======== aux role: xl_new via verified map_col ========
        const int aid  = bid - NCOPY - NFILL;  // 0..207
        const int tile = aid % 13;
        const int b    = aid / 13;
        const int Nb   = Nv[b];
        int* a_s0 = s_buf;        // [128]
        int* a_e0 = s_buf + 128;
        int* a_sn = s_buf + 256;
        int* a_en = s_buf + 384;
        if (tid < N_MAXC) {
            int2 se = ((const int2*)xi)[b * N_MAXC + tid];
            a_s0[tid] = se.x; a_e0[tid] = se.y;
            a_sn[tid] = ws[b * 2 * N_MAXC + tid];
            a_en[tid] = ws[b * 2 * N_MAXC + N_MAXC + tid];
        }
        __syncthreads();
        #pragma unroll
        for (int q = 0; q < 2; ++q) {
            const int t = tile * 512 + tid + q * 256;
            if (t < W_OUTC) {
                const int m = map_col_lds(t, Nb, a_s0, a_e0, a_sn, a_en);
                float v = (m >= 0) ? (float)xl[b * WW + m] : ((m == -1) ? SEP_CLASS : 0.0f);
                out[XL_OFF + b * W_OUTC + t] = v;
            }
        }
    }
}

// ---------------- fallback (no ws): round-7 fused kernel (verified) ----------------
#define TCOLS 512
#define HROWS 16
#define NTILE 13
typedef int vi4 __attribute__((ext_vector_type(4)));

__global__ __launch_bounds__(256, 4) void tb_fused(const float* __restrict__ x,
                                                   const int* __restrict__ xi,
                                                   const int* __restrict__ Nv,
                                                   const int* __restrict__ xl,
                                                   const float* __restrict__ sep_param,
                                                   float* __restrict__ out) {
    __shared__ int s_s0[N_MAXC], s_e0[N_MAXC], s_scan[N_MAXC], s_sn[N_MAXC], s_en[N_MAXC];
    __shared__ __align__(16) int s_map[TCOLS];
    const int t0  = blockIdx.x * TCOLS;
    const int h0  = blockIdx.y * HROWS;
    const int b   = blockIdx.z;
    const int tid = threadIdx.x;
    const int Nb  = Nv[b];
    int wv = 0;
    if (tid < N_MAXC) {
        int2 se = ((const int2*)xi)[b * N_MAXC + tid];
        s_s0[tid] = se.x; s_e0[tid] = se.y;
        int w = se.y - se.x; if (w < 0) w = 0;
        wv = (tid < Nb) ? w : 0;
        s_scan[tid] = wv;
    }
    __syncthreads();
    #pragma unroll
    for (int off = 1; off < N_MAXC; off <<= 1) {
        int v = 0;
        if (tid < N_MAXC && tid >= off) v = s_scan[tid - off];
        __syncthreads();
        if (tid < N_MAXC) s_scan[tid] += v;
        __syncthreads();
    }
    if (tid < N_MAXC) {
        int c = s_scan[tid];
        s_sn[tid] = c - wv + tid;
        s_en[tid] = c + tid;
    }
    __syncthreads();
    #pragma unroll
    for (int q = 0; q < 2; ++q) {
        const int j = tid + q * 256;
        const int t = t0 + j;
        s_map[j] = (t < W_OUTC) ? map_col_lds(t, Nb, s_s0, s_e0, s_sn, s_en) : -2;
    }
    if (blockIdx.y == 0 && blockIdx.x == 0 && tid < N_MAXC) {
        const bool valid = tid < Nb;
        out[XI_OFF + (b * N_MAXC + tid) * 2 + 0] = valid ? (float)s_sn[tid] : 0.0f;
        out[XI_OFF + (b * N_MAXC + tid) * 2 + 1] = valid ? (float)s_en[tid] : 0.0f;
    }
    __syncthreads();
    if (blockIdx.y == 0) {
        #pragma unroll
        for (int q = 0; q < 2; ++q) {
            const int j = tid + q * 256;
            const int t = t0 + j;
            if (t < W_OUTC) {
                const int m = s_map[j];
                float v = (m >= 0) ? (float)xl[b * WW + m] : ((m == -1) ? SEP_CLASS : 0.0f);
                out[XL_OFF + b * W_OUTC + t] = v;
            }
        }
    }
    const float sep = sep_param[0];
    const int   c   = tid & 127;
    const int   rb  = tid >> 7;
    const vi4   mv  = ((const vi4*)s_map)[c];
    const int   tA  = t0 + 4 * c;
    const float* xb = x   + ((size_t)b << 20);
    float*       ob = out + (size_t)b * (HH * W_OUTC);
    const unsigned a0 = (mv.x >= 0) ? (unsigned)mv.x : 0u;
    const unsigned a1 = (mv.y >= 0) ? (unsigned)mv.y : 0u;
    const unsigned a2 = (mv.z >= 0) ? (unsigned)mv.z : 0u;
    const unsigned a3 = (mv.w >= 0) ? (unsigned)mv.w : 0u;
    const float f0 = (mv.x == -1) ? sep : 0.0f;
    const float f1 = (mv.y == -1) ? sep : 0.0f;
    const float f2 = (mv.z == -1) ? sep : 0.0f;
    const float f3 = (mv.w == -1) ? sep : 0.0f;
    if (tA + 3 < W_OUTC) {
        #pragma unroll
        for (int rr = 0; rr < HROWS / 2; ++rr) {
            const int h = h0 + rb + rr * 2;
            const float* xr = xb + ((size_t)h << 13);
            float* orow = ob + (size_t)h * W_OUTC + tA;
            const float v0 = (mv.x >= 0) ? xr[a0] : f0;
            const float v1 = (mv.y >= 0) ? xr[a1] : f1;
            const float v2 = (mv.z >= 0) ? xr[a2] : f2;
            const float v3 = (mv.w >= 0) ? xr[a3] : f3;
            orow[0] = v0; orow[1] = v1; orow[2] = v2; orow[3] = v3;
        }
    } else if (tA < W_OUTC) {
        const int nrem = W_OUTC - tA;
        #pragma unroll
        for (int rr = 0; rr < HROWS / 2; ++rr) {
            const int h = h0 + rb + rr * 2;
            const float* xr = xb + ((size_t)h << 13);
            float* orow = ob + (size_t)h * W_OUTC + tA;
            if (nrem > 0) orow[0] = (mv.x >= 0) ? xr[a0] : f0;
            if (nrem > 1) orow[1] = (mv.y >= 0) ? xr[a1] : f1;
            if (nrem > 2) orow[2] = (mv.z >= 0) ? xr[a2] : f2;
        }
    }
}

extern "C" void kernel_launch(void* const* d_in, const int* in_sizes, int n_in,
                              void* d_out, int out_size, void* d_ws, size_t ws_size,
                              hipStream_t stream) {
    const float* x   = (const float*)d_in[0];
    const int*   xi  = (const int*)  d_in[1];
    const int*   Nv  = (const int*)  d_in[2];
    const int*   xl  = (const int*)  d_in[3];
    const float* sep = (const float*)d_in[4];
    float*       out = (float*)d_out;

    if (d_ws && ws_size >= WS_INTS * sizeof(int)) {
        int* ws = (int*)d_ws;
        tb_scan<<<dim3(BB), dim3(128), 0, stream>>>(xi, Nv, out, ws);
        tb_main<<<dim3(NBLK), dim3(256), 0, stream>>>(x, xi, Nv, xl, sep, ws, out);
    } else {
        dim3 grid(NTILE, HH / HROWS, BB);
        tb_fused<<<grid, dim3(256), 0, stream>>>(x, xi, Nv, xl, sep, out);
    }
}